// Round 1
// baseline (1595.501 us; speedup 1.0000x reference)
//
#include <hip/hip_runtime.h>
#include <math.h>

// Problem constants (match reference)
#define N_NODES 20000
#define N_EDGES 320000
#define D_IN    512
#define D_HID   128
#define N_HEADS 8
#define N_CLS   64

__device__ __forceinline__ float leaky(float x) { return fmaxf(x, 0.01f * x); }

// ---------------- CSR build (rebuilt every call; d_ws is re-poisoned) ----------------
__global__ void k_zero(int* __restrict__ p, int n) {
    int i = blockIdx.x * blockDim.x + threadIdx.x;
    if (i < n) p[i] = 0;
}

__global__ void k_count(const int* __restrict__ dst, int* __restrict__ counts, int e) {
    int i = blockIdx.x * blockDim.x + threadIdx.x;
    if (i < e) atomicAdd(&counts[dst[i]], 1);
}

// Single-block exclusive scan over counts -> indptr, cursor. N=20000 -> 20 chunks of 1024.
__global__ void k_scan(const int* __restrict__ counts, int* __restrict__ indptr,
                       int* __restrict__ cursor, int n) {
    __shared__ int sdata[1024];
    __shared__ int srun;
    int t = threadIdx.x;
    if (t == 0) srun = 0;
    __syncthreads();
    for (int base = 0; base < n; base += 1024) {
        int idx = base + t;
        int v = (idx < n) ? counts[idx] : 0;
        sdata[t] = v;
        __syncthreads();
        for (int off = 1; off < 1024; off <<= 1) {
            int x = (t >= off) ? sdata[t - off] : 0;
            __syncthreads();
            sdata[t] += x;
            __syncthreads();
        }
        int incl = sdata[t];
        int run = srun;
        if (idx < n) {
            indptr[idx] = run + incl - v;
            cursor[idx] = run + incl - v;
        }
        __syncthreads();
        if (t == 1023) srun = run + incl;
        __syncthreads();
    }
    if (t == 0) indptr[n] = srun;
}

__global__ void k_scatter(const int* __restrict__ src, const int* __restrict__ dst,
                          int* __restrict__ cursor, int* __restrict__ csr_src, int e) {
    int i = blockIdx.x * blockDim.x + threadIdx.x;
    if (i < e) {
        int pos = atomicAdd(&cursor[dst[i]], 1);
        csr_src[pos] = src[i];
    }
}

// ---------------- fp32 tiled GEMM: C[m, hb*strideC + n] = A[m,:K] @ B_h[:,n] + bias_h[n]
// Block tile 128x128, BK=16, 256 threads, 8x8 micro-tile per thread.
#define BM 128
#define BN 128
#define BK 16
__global__ __launch_bounds__(256) void k_sgemm_bias(
    const float* __restrict__ A, const float* __restrict__ B,
    const float* __restrict__ bias, float* __restrict__ C,
    int M, int K, int Ncols, int ldb, int ldc,
    long strideB, int strideBias, int strideC)
{
    __shared__ float As[BK][BM + 4];   // transposed A tile, padded
    __shared__ float Bs[BK][BN];

    const int tid = threadIdx.x;
    const int hb  = blockIdx.z;
    const float* Bh    = B    + (size_t)hb * strideB;
    const float* biash = bias + (size_t)hb * strideBias;
    float*       Ch    = C    + (size_t)hb * strideC;

    const int m0 = blockIdx.x * BM;
    const int tx = tid & 15;   // n direction (16 threads x 8 cols = 128)
    const int ty = tid >> 4;   // m direction (16 threads x 8 rows = 128)

    float acc[8][8];
#pragma unroll
    for (int i = 0; i < 8; ++i)
#pragma unroll
        for (int j = 0; j < 8; ++j) acc[i][j] = 0.f;

    for (int k0 = 0; k0 < K; k0 += BK) {
        // A tile: 128 rows x 16 cols. 2 passes x (64 rows x 4 threads x float4)
#pragma unroll
        for (int p = 0; p < 2; ++p) {
            int r = (tid >> 2) + p * 64;       // 0..127
            int c = (tid & 3) * 4;             // 0,4,8,12
            int gm = m0 + r;
            float4 v = make_float4(0.f, 0.f, 0.f, 0.f);
            if (gm < M) v = *(const float4*)(A + (size_t)gm * K + k0 + c);
            As[c + 0][r] = v.x;
            As[c + 1][r] = v.y;
            As[c + 2][r] = v.z;
            As[c + 3][r] = v.w;
        }
        // B tile: 16 rows x 128 cols. 2 passes x (8 rows x 32 threads x float4)
#pragma unroll
        for (int p = 0; p < 2; ++p) {
            int r = (tid >> 5) + p * 8;        // 0..15
            int c = (tid & 31) * 4;            // 0..124
            float4 v = make_float4(0.f, 0.f, 0.f, 0.f);
            if (c < Ncols) v = *(const float4*)(Bh + (size_t)(k0 + r) * ldb + c);
            *(float4*)&Bs[r][c] = v;
        }
        __syncthreads();

#pragma unroll
        for (int kk = 0; kk < BK; ++kk) {
            float a[8], b[8];
            *(float4*)&a[0] = *(const float4*)&As[kk][ty * 8];
            *(float4*)&a[4] = *(const float4*)&As[kk][ty * 8 + 4];
            *(float4*)&b[0] = *(const float4*)&Bs[kk][tx * 8];
            *(float4*)&b[4] = *(const float4*)&Bs[kk][tx * 8 + 4];
#pragma unroll
            for (int i = 0; i < 8; ++i)
#pragma unroll
                for (int j = 0; j < 8; ++j)
                    acc[i][j] += a[i] * b[j];
        }
        __syncthreads();
    }

    // epilogue: bias add, vectorized store
    const int gn0 = tx * 8;
    if (gn0 < Ncols) {
        float4 bv0, bv1;
        bv0 = *(const float4*)&biash[gn0];
        bv1 = *(const float4*)&biash[gn0 + 4];
#pragma unroll
        for (int i = 0; i < 8; ++i) {
            int gm = m0 + ty * 8 + i;
            if (gm >= M) continue;
            float* cp = Ch + (size_t)gm * ldc + gn0;
            float4 v0 = make_float4(acc[i][0] + bv0.x, acc[i][1] + bv0.y,
                                    acc[i][2] + bv0.z, acc[i][3] + bv0.w);
            float4 v1 = make_float4(acc[i][4] + bv1.x, acc[i][5] + bv1.y,
                                    acc[i][6] + bv1.z, acc[i][7] + bv1.w);
            *(float4*)cp       = v0;
            *(float4*)(cp + 4) = v1;
        }
    }
}

// ---------------- per-node attention logits: a1[n,h] = ft[n,h,:]·al[h] + alb[h], same for a2/ar
// One wave per node; both dots share the single ft load.
__global__ __launch_bounds__(256) void k_alogit(
    const float* __restrict__ ft, const float* __restrict__ al,
    const float* __restrict__ alb, const float* __restrict__ ar,
    const float* __restrict__ arb, float* __restrict__ a1,
    float* __restrict__ a2, int H_, int Dh)
{
    int n = blockIdx.x * 4 + (threadIdx.x >> 6);
    int lane = threadIdx.x & 63;
    if (n >= N_NODES) return;
    int ld = H_ * Dh;
    for (int h = 0; h < H_; ++h) {
        float s1 = 0.f, s2 = 0.f;
        for (int j = lane; j < Dh; j += 64) {
            float f = ft[(size_t)n * ld + h * Dh + j];
            s1 += f * al[h * Dh + j];
            s2 += f * ar[h * Dh + j];
        }
#pragma unroll
        for (int off = 32; off > 0; off >>= 1) {
            s1 += __shfl_xor(s1, off);
            s2 += __shfl_xor(s2, off);
        }
        if (lane == 0) {
            a1[n * H_ + h] = s1 + alb[h];
            a2[n * H_ + h] = s2 + arb[h];
        }
    }
}

// ---------------- edge softmax + aggregation + ELU. One wave per (dst node, head).
// Two in-wave passes (max, then weight+accumulate). No global atomics.
__global__ __launch_bounds__(256) void k_aggregate(
    const float* __restrict__ ft, const float* __restrict__ a1,
    const float* __restrict__ a2, const int* __restrict__ indptr,
    const int* __restrict__ csr_src, float* __restrict__ out,
    int H_, int Dh)
{
    int w = blockIdx.x * 4 + (threadIdx.x >> 6);
    int lane = threadIdx.x & 63;
    int n = w / H_;
    int h = w - n * H_;
    if (n >= N_NODES) return;
    int ld = H_ * Dh;
    int start = indptr[n], end = indptr[n + 1];
    float* op = out + (size_t)n * ld + h * Dh;
    if (end <= start) {     // no incoming edges (shouldn't happen: dst includes arange(N))
        op[lane] = 0.f;
        if (Dh == 128) op[lane + 64] = 0.f;
        return;
    }
    float a1v = a1[n * H_ + h];

    // pass 1: segment max
    float m = -INFINITY;
    for (int e = start + lane; e < end; e += 64) {
        float s = leaky(a1v + a2[csr_src[e] * H_ + h]);
        m = fmaxf(m, s);
    }
#pragma unroll
    for (int off = 32; off > 0; off >>= 1) m = fmaxf(m, __shfl_xor(m, off));

    // pass 2: weights (chunk of <=64 in parallel), then broadcast + coalesced accumulate
    float denom = 0.f, acc0 = 0.f, acc1 = 0.f;
    for (int base = start; base < end; base += 64) {
        int e = base + lane;
        float wgt = 0.f;
        int sidx = 0;
        if (e < end) {
            sidx = csr_src[e];
            wgt = expf(leaky(a1v + a2[sidx * H_ + h]) - m);
        }
        denom += wgt;
        int cnt = min(64, end - base);
        for (int i = 0; i < cnt; ++i) {
            float wi = __shfl(wgt, i);
            int si  = __shfl(sidx, i);
            const float* fp = ft + (size_t)si * ld + h * Dh;
            acc0 += wi * fp[lane];
            if (Dh == 128) acc1 += wi * fp[lane + 64];
        }
    }
#pragma unroll
    for (int off = 32; off > 0; off >>= 1) denom += __shfl_xor(denom, off);
    float inv = 1.f / denom;

    float r0 = acc0 * inv;
    op[lane] = (r0 > 0.f) ? r0 : expm1f(r0);
    if (Dh == 128) {
        float r1 = acc1 * inv;
        op[lane + 64] = (r1 > 0.f) ? r1 : expm1f(r1);
    }
}

// ---------------- launch ----------------
extern "C" void kernel_launch(void* const* d_in, const int* in_sizes, int n_in,
                              void* d_out, int out_size, void* d_ws, size_t ws_size,
                              hipStream_t stream) {
    const float* features = (const float*)d_in[0];
    const int*   src      = (const int*)d_in[1];
    const int*   dst      = (const int*)d_in[2];
    const float* W0  = (const float*)d_in[3];
    const float* b0  = (const float*)d_in[4];
    const float* al0 = (const float*)d_in[5];
    const float* alb0= (const float*)d_in[6];
    const float* ar0 = (const float*)d_in[7];
    const float* arb0= (const float*)d_in[8];
    const float* W1  = (const float*)d_in[9];
    const float* b1  = (const float*)d_in[10];
    const float* al1 = (const float*)d_in[11];
    const float* alb1= (const float*)d_in[12];
    const float* ar1 = (const float*)d_in[13];
    const float* arb1= (const float*)d_in[14];
    const float* Wf  = (const float*)d_in[15];
    const float* bff = (const float*)d_in[16];
    const float* alf = (const float*)d_in[17];
    const float* albf= (const float*)d_in[18];
    const float* arf = (const float*)d_in[19];
    const float* arbf= (const float*)d_in[20];
    float* out = (float*)d_out;

    // workspace carve (all 16B-aligned)
    const size_t NF = (size_t)N_NODES * N_HEADS * D_HID;  // 20.48M floats
    float* ft = (float*)d_ws;
    float* xb = ft + NF;
    float* a1 = xb + NF;
    float* a2 = a1 + (size_t)N_NODES * N_HEADS;
    int* counts = (int*)(a2 + (size_t)N_NODES * N_HEADS);
    int* indptr = counts + N_NODES;
    int* cursor = indptr + N_NODES + 1;
    int* csr    = cursor + N_NODES;                       // E entries

    // ---- CSR build
    k_zero<<<(N_NODES + 255) / 256, 256, 0, stream>>>(counts, N_NODES);
    k_count<<<(N_EDGES + 255) / 256, 256, 0, stream>>>(dst, counts, N_EDGES);
    k_scan<<<1, 1024, 0, stream>>>(counts, indptr, cursor, N_NODES);
    k_scatter<<<(N_EDGES + 255) / 256, 256, 0, stream>>>(src, dst, cursor, csr, N_EDGES);

    const int gm = (N_NODES + BM - 1) / BM;  // 157
    dim3 gemm_grid_h(gm, 1, N_HEADS);
    dim3 gemm_grid_1(gm, 1, 1);
    int nodeBlocks = (N_NODES + 3) / 4;           // 5000
    int aggBlocksH = (N_NODES * N_HEADS + 3) / 4; // 40000

    // ---- layer 0: features [N,512] -> ft [N, 8*128]
    k_sgemm_bias<<<gemm_grid_h, 256, 0, stream>>>(
        features, W0, b0, ft, N_NODES, D_IN, D_HID, D_HID, N_HEADS * D_HID,
        (long)D_IN * D_HID, D_HID, D_HID);
    k_alogit<<<nodeBlocks, 256, 0, stream>>>(ft, al0, alb0, ar0, arb0, a1, a2, N_HEADS, D_HID);
    k_aggregate<<<aggBlocksH, 256, 0, stream>>>(ft, a1, a2, indptr, csr, xb, N_HEADS, D_HID);

    // ---- layer 1: xb [N,1024] -> ft [N, 8*128]
    k_sgemm_bias<<<gemm_grid_h, 256, 0, stream>>>(
        xb, W1, b1, ft, N_NODES, N_HEADS * D_HID, D_HID, D_HID, N_HEADS * D_HID,
        (long)N_HEADS * D_HID * D_HID, D_HID, D_HID);
    k_alogit<<<nodeBlocks, 256, 0, stream>>>(ft, al1, alb1, ar1, arb1, a1, a2, N_HEADS, D_HID);
    k_aggregate<<<aggBlocksH, 256, 0, stream>>>(ft, a1, a2, indptr, csr, xb, N_HEADS, D_HID);

    // ---- final: xb [N,1024] -> ft [N,64] -> out [N,64]
    k_sgemm_bias<<<gemm_grid_1, 256, 0, stream>>>(
        xb, Wf, bff, ft, N_NODES, N_HEADS * D_HID, N_CLS, N_CLS, N_CLS, 0, 0, 0);
    k_alogit<<<nodeBlocks, 256, 0, stream>>>(ft, alf, albf, arf, arbf, a1, a2, 1, N_CLS);
    k_aggregate<<<nodeBlocks, 256, 0, stream>>>(ft, a1, a2, indptr, csr, out, 1, N_CLS);
}

// Round 2
// 824.042 us; speedup vs baseline: 1.9362x; 1.9362x over previous
//
#include <hip/hip_runtime.h>
#include <math.h>

// Problem constants (match reference)
#define N_NODES 20000
#define N_EDGES 320000
#define D_IN    512
#define D_HID   128
#define N_HEADS 8
#define N_CLS   64

typedef __bf16 bf16x8 __attribute__((ext_vector_type(8)));
typedef float  f32x4  __attribute__((ext_vector_type(4)));

__device__ __forceinline__ float leaky(float x) { return fmaxf(x, 0.01f * x); }

// fp32 -> bf16 round-to-nearest-even
__device__ __forceinline__ unsigned short f2bf(float f) {
    unsigned u = __float_as_uint(f);
    return (unsigned short)((u + 0x7FFFu + ((u >> 16) & 1u)) >> 16);
}

// async global->LDS, 16B per lane. l must be the wave-uniform base (lane0 slot);
// HW writes lane i at l + i*16. g is per-lane.
__device__ __forceinline__ void gl_lds16(const void* g, void* l) {
    __builtin_amdgcn_global_load_lds((const __attribute__((address_space(1))) void*)g,
                                     (__attribute__((address_space(3))) void*)l, 16, 0, 0);
}

// ---------------- CSR build (rebuilt every call) ----------------
__global__ void k_zero(int* __restrict__ p, int n) {
    int i = blockIdx.x * blockDim.x + threadIdx.x;
    if (i < n) p[i] = 0;
}

__global__ void k_count(const int* __restrict__ dst, int* __restrict__ counts, int e) {
    int i = blockIdx.x * blockDim.x + threadIdx.x;
    if (i < e) atomicAdd(&counts[dst[i]], 1);
}

__global__ void k_scan(const int* __restrict__ counts, int* __restrict__ indptr,
                       int* __restrict__ cursor, int n) {
    __shared__ int sdata[1024];
    __shared__ int srun;
    int t = threadIdx.x;
    if (t == 0) srun = 0;
    __syncthreads();
    for (int base = 0; base < n; base += 1024) {
        int idx = base + t;
        int v = (idx < n) ? counts[idx] : 0;
        sdata[t] = v;
        __syncthreads();
        for (int off = 1; off < 1024; off <<= 1) {
            int x = (t >= off) ? sdata[t - off] : 0;
            __syncthreads();
            sdata[t] += x;
            __syncthreads();
        }
        int incl = sdata[t];
        int run = srun;
        if (idx < n) {
            indptr[idx] = run + incl - v;
            cursor[idx] = run + incl - v;
        }
        __syncthreads();
        if (t == 1023) srun = run + incl;
        __syncthreads();
    }
    if (t == 0) indptr[n] = srun;
}

__global__ void k_scatter(const int* __restrict__ src, const int* __restrict__ dst,
                          int* __restrict__ cursor, int* __restrict__ csr_src, int e) {
    int i = blockIdx.x * blockDim.x + threadIdx.x;
    if (i < e) {
        int pos = atomicAdd(&cursor[dst[i]], 1);
        csr_src[pos] = src[i];
    }
}

// ---------------- conversions ----------------
// fp32 [n4*4] -> bf16, vectorized
__global__ void k_cvtA(const float* __restrict__ in, unsigned short* __restrict__ out, int n4) {
    int i = blockIdx.x * blockDim.x + threadIdx.x;
    if (i < n4) {
        float4 v = ((const float4*)in)[i];
        unsigned long long pk =
            (unsigned long long)f2bf(v.x) | ((unsigned long long)f2bf(v.y) << 16) |
            ((unsigned long long)f2bf(v.z) << 32) | ((unsigned long long)f2bf(v.w) << 48);
        *(unsigned long long*)(out + (size_t)i * 4) = pk;
    }
}

// W [h][K][Nf] fp32 -> Wt [h][Nf][K] bf16 (64x64 LDS tile transpose)
__global__ void k_cvtW(const float* __restrict__ W, unsigned short* __restrict__ Wt,
                       int K, int Nf) {
    __shared__ float t[64][65];
    int k0 = blockIdx.x * 64, n0 = blockIdx.y * 64, h = blockIdx.z;
    const float* Wh = W + (size_t)h * K * Nf;
    unsigned short* Wth = Wt + (size_t)h * K * Nf;
    int tx = threadIdx.x & 63, ty = threadIdx.x >> 6;
#pragma unroll
    for (int i = 0; i < 16; ++i) {
        int k = ty + i * 4;
        t[k][tx] = Wh[(size_t)(k0 + k) * Nf + n0 + tx];
    }
    __syncthreads();
#pragma unroll
    for (int i = 0; i < 16; ++i) {
        int n = ty + i * 4;
        Wth[(size_t)(n0 + n) * K + k0 + tx] = f2bf(t[tx][n]);
    }
}

// ---------------- bf16 MFMA GEMM ----------------
// C[m, h*BN + n] = A[m,:K](bf16) @ Bt_h[n,:K](bf16)^T + bias_h[n]
// BM=128, BK=64, 4 waves. LDS staged via global_load_lds (linear dest) with
// XOR-swizzled SOURCE cols; ds_read_b128 applies the same XOR -> 2-way max.
template<int BN>
__global__ __launch_bounds__(256) void k_gemm_bf16(
    const unsigned short* __restrict__ A, const unsigned short* __restrict__ Bt,
    const float* __restrict__ bias, float* __restrict__ C,
    int M, int K, int ldc)
{
    constexpr int BM = 128, BK = 64;
    constexpr int WN    = (BN == 128) ? 2 : 1;   // waves along N
    constexpr int MFRAG = (BN == 128) ? 4 : 2;   // 16-row frags per wave
    constexpr int NFRAG = 4;                     // 16-col frags per wave

    __shared__ unsigned short As[BM * BK];   // 16 KB
    __shared__ unsigned short Bs[BN * BK];   // 16/8 KB

    const int tid  = threadIdx.x;
    const int lane = tid & 63;
    const int wid  = tid >> 6;
    const int wm   = wid / WN;
    const int wn   = wid % WN;
    const int m0   = blockIdx.x * BM;
    const int h    = blockIdx.z;

    const unsigned short* Bth = Bt + (size_t)h * BN * K;
    const float* biash = bias + h * BN;

    const int rsub = lane & 15;
    const int rhi  = lane >> 4;
    const int wbase = (tid & ~63);   // wave-uniform lane0 slot

    f32x4 acc[MFRAG][NFRAG];
#pragma unroll
    for (int i = 0; i < MFRAG; ++i)
#pragma unroll
        for (int j = 0; j < NFRAG; ++j) acc[i][j] = (f32x4){0.f, 0.f, 0.f, 0.f};

    for (int k0 = 0; k0 < K; k0 += BK) {
        // ---- stage A: 128 rows x 64 bf16 (128B/row), 4 issues x 256 lanes x 16B
#pragma unroll
        for (int p = 0; p < 4; ++p) {
            int o    = (p * 256 + tid) * 16;               // linear LDS byte slot
            int row  = o >> 7;
            int icol = (o & 127) ^ ((row & 7) << 4);       // inverse-swizzled source col (bytes)
            int grow = m0 + row; if (grow > M - 1) grow = M - 1;
            gl_lds16(A + (size_t)grow * K + k0 + (icol >> 1),
                     (void*)((char*)As + (p * 256 + wbase) * 16));
        }
        // ---- stage B: BN rows x 64 bf16
#pragma unroll
        for (int p = 0; p < BN / 32; ++p) {
            int o    = (p * 256 + tid) * 16;
            int row  = o >> 7;
            int icol = (o & 127) ^ ((row & 7) << 4);
            gl_lds16(Bth + (size_t)row * K + k0 + (icol >> 1),
                     (void*)((char*)Bs + (p * 256 + wbase) * 16));
        }
        __syncthreads();   // drains vmcnt (compiler-emitted) -> LDS valid

        // ---- fragments (swizzled ds_read_b128) + MFMA
        bf16x8 av[2][MFRAG], bv[2][NFRAG];
#pragma unroll
        for (int q = 0; q < 2; ++q) {
#pragma unroll
            for (int mi = 0; mi < MFRAG; ++mi) {
                int row  = wm * (MFRAG * 16) + mi * 16 + rsub;
                int icol = (q * 64 + rhi * 16) ^ ((row & 7) << 4);
                av[q][mi] = *(const bf16x8*)((const char*)As + row * 128 + icol);
            }
#pragma unroll
            for (int ni = 0; ni < NFRAG; ++ni) {
                int row  = wn * (NFRAG * 16) + ni * 16 + rsub;
                int icol = (q * 64 + rhi * 16) ^ ((row & 7) << 4);
                bv[q][ni] = *(const bf16x8*)((const char*)Bs + row * 128 + icol);
            }
        }
#pragma unroll
        for (int q = 0; q < 2; ++q)
#pragma unroll
            for (int mi = 0; mi < MFRAG; ++mi)
#pragma unroll
                for (int ni = 0; ni < NFRAG; ++ni)
                    acc[mi][ni] = __builtin_amdgcn_mfma_f32_16x16x32_bf16(
                        av[q][mi], bv[q][ni], acc[mi][ni], 0, 0, 0);
        __syncthreads();
    }

    // ---- epilogue: C/D layout col=lane&15, row=(lane>>4)*4+reg
#pragma unroll
    for (int ni = 0; ni < NFRAG; ++ni) {
        int col  = wn * (NFRAG * 16) + ni * 16 + rsub;
        float bvv = biash[col];
        int gcol = h * BN + col;
#pragma unroll
        for (int mi = 0; mi < MFRAG; ++mi) {
            int rowb = m0 + wm * (MFRAG * 16) + mi * 16 + rhi * 4;
#pragma unroll
            for (int r = 0; r < 4; ++r) {
                int row = rowb + r;
                if (row < M) C[(size_t)row * ldc + gcol] = acc[mi][ni][r] + bvv;
            }
        }
    }
}

// ---------------- per-node attention logits (fp32 ft) ----------------
__global__ __launch_bounds__(256) void k_alogit(
    const float* __restrict__ ft, const float* __restrict__ al,
    const float* __restrict__ alb, const float* __restrict__ ar,
    const float* __restrict__ arb, float* __restrict__ a1,
    float* __restrict__ a2, int H_, int Dh)
{
    int n = blockIdx.x * 4 + (threadIdx.x >> 6);
    int lane = threadIdx.x & 63;
    if (n >= N_NODES) return;
    int ld = H_ * Dh;
    for (int h = 0; h < H_; ++h) {
        float s1 = 0.f, s2 = 0.f;
        for (int j = lane; j < Dh; j += 64) {
            float f = ft[(size_t)n * ld + h * Dh + j];
            s1 += f * al[h * Dh + j];
            s2 += f * ar[h * Dh + j];
        }
#pragma unroll
        for (int off = 32; off > 0; off >>= 1) {
            s1 += __shfl_xor(s1, off);
            s2 += __shfl_xor(s2, off);
        }
        if (lane == 0) {
            a1[n * H_ + h] = s1 + alb[h];
            a2[n * H_ + h] = s2 + arb[h];
        }
    }
}

// ---------------- edge softmax + aggregation + ELU ----------------
// One wave per (dst node, head). OUT_BF16: write bf16 (feeds next GEMM).
template<int OUT_BF16>
__global__ __launch_bounds__(256) void k_aggregate(
    const float* __restrict__ ft, const float* __restrict__ a1,
    const float* __restrict__ a2, const int* __restrict__ indptr,
    const int* __restrict__ csr_src, void* __restrict__ outp,
    int H_, int Dh)
{
    int w = blockIdx.x * 4 + (threadIdx.x >> 6);
    int lane = threadIdx.x & 63;
    int n = w / H_;
    int h = w - n * H_;
    if (n >= N_NODES) return;
    int ld = H_ * Dh;
    size_t obase = (size_t)n * ld + h * Dh;
    int start = indptr[n], end = indptr[n + 1];

    auto store = [&](int idx, float v) {
        if (OUT_BF16) ((unsigned short*)outp)[obase + idx] = f2bf(v);
        else          ((float*)outp)[obase + idx] = v;
    };

    if (end <= start) {
        store(lane, 0.f);
        if (Dh == 128) store(lane + 64, 0.f);
        return;
    }
    float a1v = a1[n * H_ + h];

    // pass 1: segment max
    float m = -INFINITY;
    for (int e = start + lane; e < end; e += 64) {
        float s = leaky(a1v + a2[csr_src[e] * H_ + h]);
        m = fmaxf(m, s);
    }
#pragma unroll
    for (int off = 32; off > 0; off >>= 1) m = fmaxf(m, __shfl_xor(m, off));

    // pass 2: weights + broadcast + coalesced accumulate
    float denom = 0.f, acc0 = 0.f, acc1 = 0.f;
    for (int base = start; base < end; base += 64) {
        int e = base + lane;
        float wgt = 0.f;
        int sidx = 0;
        if (e < end) {
            sidx = csr_src[e];
            wgt = expf(leaky(a1v + a2[sidx * H_ + h]) - m);
        }
        denom += wgt;
        int cnt = min(64, end - base);
        for (int i = 0; i < cnt; ++i) {
            float wi = __shfl(wgt, i);
            int si  = __shfl(sidx, i);
            const float* fp = ft + (size_t)si * ld + h * Dh;
            acc0 += wi * fp[lane];
            if (Dh == 128) acc1 += wi * fp[lane + 64];
        }
    }
#pragma unroll
    for (int off = 32; off > 0; off >>= 1) denom += __shfl_xor(denom, off);
    float inv = 1.f / denom;

    float r0 = acc0 * inv;
    store(lane, (r0 > 0.f) ? r0 : expm1f(r0));
    if (Dh == 128) {
        float r1 = acc1 * inv;
        store(lane + 64, (r1 > 0.f) ? r1 : expm1f(r1));
    }
}

// ---------------- launch ----------------
extern "C" void kernel_launch(void* const* d_in, const int* in_sizes, int n_in,
                              void* d_out, int out_size, void* d_ws, size_t ws_size,
                              hipStream_t stream) {
    const float* features = (const float*)d_in[0];
    const int*   src      = (const int*)d_in[1];
    const int*   dst      = (const int*)d_in[2];
    const float* W0  = (const float*)d_in[3];
    const float* b0  = (const float*)d_in[4];
    const float* al0 = (const float*)d_in[5];
    const float* alb0= (const float*)d_in[6];
    const float* ar0 = (const float*)d_in[7];
    const float* arb0= (const float*)d_in[8];
    const float* W1  = (const float*)d_in[9];
    const float* b1  = (const float*)d_in[10];
    const float* al1 = (const float*)d_in[11];
    const float* alb1= (const float*)d_in[12];
    const float* ar1 = (const float*)d_in[13];
    const float* arb1= (const float*)d_in[14];
    const float* Wf  = (const float*)d_in[15];
    const float* bff = (const float*)d_in[16];
    const float* alf = (const float*)d_in[17];
    const float* albf= (const float*)d_in[18];
    const float* arf = (const float*)d_in[19];
    const float* arbf= (const float*)d_in[20];
    float* out = (float*)d_out;

    // workspace carve (regions 16B-aligned by construction)
    char* wp = (char*)d_ws;
    float* ftf            = (float*)wp;           wp += (size_t)N_NODES * 1024 * 4;  // fp32 GEMM out
    unsigned short* xb16  = (unsigned short*)wp;  wp += (size_t)N_NODES * 1024 * 2;  // bf16 agg out
    unsigned short* feat16= (unsigned short*)wp;  wp += (size_t)N_NODES * 512 * 2;
    unsigned short* w0t   = (unsigned short*)wp;  wp += (size_t)N_HEADS * D_HID * D_IN * 2;
    unsigned short* w1t   = (unsigned short*)wp;  wp += (size_t)N_HEADS * D_HID * 1024 * 2;
    unsigned short* wft   = (unsigned short*)wp;  wp += (size_t)N_CLS * 1024 * 2;
    float* a1             = (float*)wp;           wp += (size_t)N_NODES * N_HEADS * 4;
    float* a2             = (float*)wp;           wp += (size_t)N_NODES * N_HEADS * 4;
    int* counts = (int*)wp;                       wp += (size_t)N_NODES * 4;
    int* indptr = (int*)wp;                       wp += (size_t)(N_NODES + 1) * 4;
    int* cursor = (int*)wp;                       wp += (size_t)N_NODES * 4;
    int* csr    = (int*)wp;

    // ---- CSR build
    k_zero<<<(N_NODES + 255) / 256, 256, 0, stream>>>(counts, N_NODES);
    k_count<<<(N_EDGES + 255) / 256, 256, 0, stream>>>(dst, counts, N_EDGES);
    k_scan<<<1, 1024, 0, stream>>>(counts, indptr, cursor, N_NODES);
    k_scatter<<<(N_EDGES + 255) / 256, 256, 0, stream>>>(src, dst, cursor, csr, N_EDGES);

    // ---- conversions
    k_cvtA<<<(N_NODES * D_IN / 4 + 255) / 256, 256, 0, stream>>>(features, feat16, N_NODES * D_IN / 4);
    k_cvtW<<<dim3(D_IN / 64, D_HID / 64, N_HEADS), 256, 0, stream>>>(W0, w0t, D_IN, D_HID);
    k_cvtW<<<dim3(1024 / 64, D_HID / 64, N_HEADS), 256, 0, stream>>>(W1, w1t, 1024, D_HID);
    k_cvtW<<<dim3(1024 / 64, N_CLS / 64, 1), 256, 0, stream>>>(Wf, wft, 1024, N_CLS);

    const int gm = (N_NODES + 127) / 128;           // 157
    int nodeBlocks = (N_NODES + 3) / 4;             // 5000
    int aggBlocksH = (N_NODES * N_HEADS + 3) / 4;   // 40000

    // ---- layer 0
    k_gemm_bf16<128><<<dim3(gm, 1, N_HEADS), 256, 0, stream>>>(
        feat16, w0t, b0, ftf, N_NODES, D_IN, N_HEADS * D_HID);
    k_alogit<<<nodeBlocks, 256, 0, stream>>>(ftf, al0, alb0, ar0, arb0, a1, a2, N_HEADS, D_HID);
    k_aggregate<1><<<aggBlocksH, 256, 0, stream>>>(ftf, a1, a2, indptr, csr, xb16, N_HEADS, D_HID);

    // ---- layer 1
    k_gemm_bf16<128><<<dim3(gm, 1, N_HEADS), 256, 0, stream>>>(
        xb16, w1t, b1, ftf, N_NODES, 1024, N_HEADS * D_HID);
    k_alogit<<<nodeBlocks, 256, 0, stream>>>(ftf, al1, alb1, ar1, arb1, a1, a2, N_HEADS, D_HID);
    k_aggregate<1><<<aggBlocksH, 256, 0, stream>>>(ftf, a1, a2, indptr, csr, xb16, N_HEADS, D_HID);

    // ---- final layer (N=64, single head)
    k_gemm_bf16<64><<<dim3(gm, 1, 1), 256, 0, stream>>>(
        xb16, wft, bff, ftf, N_NODES, 1024, N_CLS);
    k_alogit<<<nodeBlocks, 256, 0, stream>>>(ftf, alf, albf, arf, arbf, a1, a2, 1, N_CLS);
    k_aggregate<0><<<nodeBlocks, 256, 0, stream>>>(ftf, a1, a2, indptr, csr, out, 1, N_CLS);
}

// Round 3
// 657.084 us; speedup vs baseline: 2.4282x; 1.2541x over previous
//
#include <hip/hip_runtime.h>
#include <math.h>

// Problem constants (match reference)
#define N_NODES 20000
#define N_EDGES 320000
#define D_IN    512
#define D_HID   128
#define N_HEADS 8
#define N_CLS   64

typedef __bf16 bf16x8 __attribute__((ext_vector_type(8)));
typedef float  f32x4  __attribute__((ext_vector_type(4)));

__device__ __forceinline__ float leaky(float x) { return fmaxf(x, 0.01f * x); }

// fp32 -> bf16 round-to-nearest-even
__device__ __forceinline__ unsigned short f2bf(float f) {
    unsigned u = __float_as_uint(f);
    return (unsigned short)((u + 0x7FFFu + ((u >> 16) & 1u)) >> 16);
}
// unpack a uint holding 2 bf16 (little-endian: low half = even elem)
__device__ __forceinline__ float bflo(unsigned v) { return __uint_as_float(v << 16); }
__device__ __forceinline__ float bfhi(unsigned v) { return __uint_as_float(v & 0xffff0000u); }

// async global->LDS, 16B per lane. l must be the wave-uniform base (lane0 slot).
__device__ __forceinline__ void gl_lds16(const void* g, void* l) {
    __builtin_amdgcn_global_load_lds((const __attribute__((address_space(1))) void*)g,
                                     (__attribute__((address_space(3))) void*)l, 16, 0, 0);
}

// ---------------- CSR build (rebuilt every call) ----------------
__global__ void k_zero(int* __restrict__ p, int n) {
    int i = blockIdx.x * blockDim.x + threadIdx.x;
    if (i < n) p[i] = 0;
}

__global__ void k_count(const int* __restrict__ dst, int* __restrict__ counts, int e) {
    int i = blockIdx.x * blockDim.x + threadIdx.x;
    if (i < e) atomicAdd(&counts[dst[i]], 1);
}

__global__ void k_scan(const int* __restrict__ counts, int* __restrict__ indptr,
                       int* __restrict__ cursor, int n) {
    __shared__ int sdata[1024];
    __shared__ int srun;
    int t = threadIdx.x;
    if (t == 0) srun = 0;
    __syncthreads();
    for (int base = 0; base < n; base += 1024) {
        int idx = base + t;
        int v = (idx < n) ? counts[idx] : 0;
        sdata[t] = v;
        __syncthreads();
        for (int off = 1; off < 1024; off <<= 1) {
            int x = (t >= off) ? sdata[t - off] : 0;
            __syncthreads();
            sdata[t] += x;
            __syncthreads();
        }
        int incl = sdata[t];
        int run = srun;
        if (idx < n) {
            indptr[idx] = run + incl - v;
            cursor[idx] = run + incl - v;
        }
        __syncthreads();
        if (t == 1023) srun = run + incl;
        __syncthreads();
    }
    if (t == 0) indptr[n] = srun;
}

__global__ void k_scatter(const int* __restrict__ src, const int* __restrict__ dst,
                          int* __restrict__ cursor, int* __restrict__ csr_src, int e) {
    int i = blockIdx.x * blockDim.x + threadIdx.x;
    if (i < e) {
        int pos = atomicAdd(&cursor[dst[i]], 1);
        csr_src[pos] = src[i];
    }
}

// ---------------- conversions ----------------
__global__ void k_cvtA(const float* __restrict__ in, unsigned short* __restrict__ out, int n4) {
    int i = blockIdx.x * blockDim.x + threadIdx.x;
    if (i < n4) {
        float4 v = ((const float4*)in)[i];
        unsigned long long pk =
            (unsigned long long)f2bf(v.x) | ((unsigned long long)f2bf(v.y) << 16) |
            ((unsigned long long)f2bf(v.z) << 32) | ((unsigned long long)f2bf(v.w) << 48);
        *(unsigned long long*)(out + (size_t)i * 4) = pk;
    }
}

// W [h][K][Nf] fp32 -> Wt [h][Nf][K] bf16
__global__ void k_cvtW(const float* __restrict__ W, unsigned short* __restrict__ Wt,
                       int K, int Nf) {
    __shared__ float t[64][65];
    int k0 = blockIdx.x * 64, n0 = blockIdx.y * 64, h = blockIdx.z;
    const float* Wh = W + (size_t)h * K * Nf;
    unsigned short* Wth = Wt + (size_t)h * K * Nf;
    int tx = threadIdx.x & 63, ty = threadIdx.x >> 6;
#pragma unroll
    for (int i = 0; i < 16; ++i) {
        int k = ty + i * 4;
        t[k][tx] = Wh[(size_t)(k0 + k) * Nf + n0 + tx];
    }
    __syncthreads();
#pragma unroll
    for (int i = 0; i < 16; ++i) {
        int n = ty + i * 4;
        Wth[(size_t)(n0 + n) * K + k0 + tx] = f2bf(t[tx][n]);
    }
}

// ---------------- bf16 MFMA GEMM, bf16 output ----------------
// C[m, h*BN + n] (bf16) = A[m,:K](bf16) @ Bt_h[n,:K](bf16)^T + bias_h[n]
template<int BN>
__global__ __launch_bounds__(256) void k_gemm_bf16(
    const unsigned short* __restrict__ A, const unsigned short* __restrict__ Bt,
    const float* __restrict__ bias, unsigned short* __restrict__ C,
    int M, int K, int ldc)
{
    constexpr int BM = 128, BK = 64;
    constexpr int WN    = (BN == 128) ? 2 : 1;
    constexpr int MFRAG = (BN == 128) ? 4 : 2;
    constexpr int NFRAG = 4;

    __shared__ unsigned short As[BM * BK];
    __shared__ unsigned short Bs[BN * BK];

    const int tid  = threadIdx.x;
    const int lane = tid & 63;
    const int wid  = tid >> 6;
    const int wm   = wid / WN;
    const int wn   = wid % WN;
    const int m0   = blockIdx.x * BM;
    const int h    = blockIdx.z;

    const unsigned short* Bth = Bt + (size_t)h * BN * K;
    const float* biash = bias + h * BN;

    const int rsub = lane & 15;
    const int rhi  = lane >> 4;
    const int wbase = (tid & ~63);

    f32x4 acc[MFRAG][NFRAG];
#pragma unroll
    for (int i = 0; i < MFRAG; ++i)
#pragma unroll
        for (int j = 0; j < NFRAG; ++j) acc[i][j] = (f32x4){0.f, 0.f, 0.f, 0.f};

    for (int k0 = 0; k0 < K; k0 += BK) {
#pragma unroll
        for (int p = 0; p < 4; ++p) {
            int o    = (p * 256 + tid) * 16;
            int row  = o >> 7;
            int icol = (o & 127) ^ ((row & 7) << 4);
            int grow = m0 + row; if (grow > M - 1) grow = M - 1;
            gl_lds16(A + (size_t)grow * K + k0 + (icol >> 1),
                     (void*)((char*)As + (p * 256 + wbase) * 16));
        }
#pragma unroll
        for (int p = 0; p < BN / 32; ++p) {
            int o    = (p * 256 + tid) * 16;
            int row  = o >> 7;
            int icol = (o & 127) ^ ((row & 7) << 4);
            gl_lds16(Bth + (size_t)row * K + k0 + (icol >> 1),
                     (void*)((char*)Bs + (p * 256 + wbase) * 16));
        }
        __syncthreads();

        bf16x8 av[2][MFRAG], bv[2][NFRAG];
#pragma unroll
        for (int q = 0; q < 2; ++q) {
#pragma unroll
            for (int mi = 0; mi < MFRAG; ++mi) {
                int row  = wm * (MFRAG * 16) + mi * 16 + rsub;
                int icol = (q * 64 + rhi * 16) ^ ((row & 7) << 4);
                av[q][mi] = *(const bf16x8*)((const char*)As + row * 128 + icol);
            }
#pragma unroll
            for (int ni = 0; ni < NFRAG; ++ni) {
                int row  = wn * (NFRAG * 16) + ni * 16 + rsub;
                int icol = (q * 64 + rhi * 16) ^ ((row & 7) << 4);
                bv[q][ni] = *(const bf16x8*)((const char*)Bs + row * 128 + icol);
            }
        }
#pragma unroll
        for (int q = 0; q < 2; ++q)
#pragma unroll
            for (int mi = 0; mi < MFRAG; ++mi)
#pragma unroll
                for (int ni = 0; ni < NFRAG; ++ni)
                    acc[mi][ni] = __builtin_amdgcn_mfma_f32_16x16x32_bf16(
                        av[q][mi], bv[q][ni], acc[mi][ni], 0, 0, 0);
        __syncthreads();
    }

    // epilogue: C/D layout col=lane&15, row=(lane>>4)*4+reg; write bf16
#pragma unroll
    for (int ni = 0; ni < NFRAG; ++ni) {
        int col  = wn * (NFRAG * 16) + ni * 16 + rsub;
        float bvv = biash[col];
        int gcol = h * BN + col;
#pragma unroll
        for (int mi = 0; mi < MFRAG; ++mi) {
            int rowb = m0 + wm * (MFRAG * 16) + mi * 16 + rhi * 4;
#pragma unroll
            for (int r = 0; r < 4; ++r) {
                int row = rowb + r;
                if (row < M) C[(size_t)row * ldc + gcol] = f2bf(acc[mi][ni][r] + bvv);
            }
        }
    }
}

// ---------------- per-node attention logits (bf16 ft) ----------------
__global__ __launch_bounds__(256) void k_alogit(
    const unsigned short* __restrict__ ft, const float* __restrict__ al,
    const float* __restrict__ alb, const float* __restrict__ ar,
    const float* __restrict__ arb, float* __restrict__ a1,
    float* __restrict__ a2, int H_, int Dh)
{
    int n = blockIdx.x * 4 + (threadIdx.x >> 6);
    int lane = threadIdx.x & 63;
    if (n >= N_NODES) return;
    int ld = H_ * Dh;
    for (int h = 0; h < H_; ++h) {
        float s1 = 0.f, s2 = 0.f;
        for (int j0 = 2 * lane; j0 < Dh; j0 += 128) {
            unsigned v = *(const unsigned*)(ft + (size_t)n * ld + h * Dh + j0);
            float lo = bflo(v), hi = bfhi(v);
            float2 A = *(const float2*)(al + h * Dh + j0);
            float2 R = *(const float2*)(ar + h * Dh + j0);
            s1 += lo * A.x + hi * A.y;
            s2 += lo * R.x + hi * R.y;
        }
#pragma unroll
        for (int off = 32; off > 0; off >>= 1) {
            s1 += __shfl_xor(s1, off);
            s2 += __shfl_xor(s2, off);
        }
        if (lane == 0) {
            a1[n * H_ + h] = s1 + alb[h];
            a2[n * H_ + h] = s2 + arb[h];
        }
    }
}

// ---------------- edge softmax + aggregation + ELU ----------------
// FINAL=0: H=8, Dh=128, bf16 out. FINAL=1: H=1, Dh=64, fp32 out.
// One wave per (dst node, head); bf16 gathers (1 uint = 2 elems per lane);
// chunk-0 logits cached from the max pass; 2 edges in flight.
template<int FINAL>
__global__ __launch_bounds__(256) void k_aggregate(
    const unsigned short* __restrict__ ft, const float* __restrict__ a1,
    const float* __restrict__ a2, const int* __restrict__ indptr,
    const int* __restrict__ csr_src, void* __restrict__ outp)
{
    constexpr int H_ = FINAL ? 1 : 8;
    constexpr int Dh = FINAL ? 64 : 128;
    constexpr int ld = H_ * Dh;

    int w = blockIdx.x * 4 + (threadIdx.x >> 6);
    int lane = threadIdx.x & 63;
    int n = w / H_;
    int h = w - n * H_;
    if (n >= N_NODES) return;
    size_t obase = (size_t)n * ld + h * Dh;
    int start = indptr[n], end = indptr[n + 1];

    if (end <= start) {
        if (FINAL) {
            if (lane < 32) *(float2*)((float*)outp + obase + 2 * (lane & 31)) = make_float2(0.f, 0.f);
        } else {
            *(unsigned*)((unsigned short*)outp + obase + 2 * lane) = 0u;
        }
        return;
    }
    float a1v = a1[n * H_ + h];

    // pass 1: segment max; cache chunk-0 logits
    int sidx0 = 0; float sv0 = 0.f;
    float m = -INFINITY;
    {
        int e = start + lane;
        if (e < end) {
            sidx0 = csr_src[e];
            sv0 = leaky(a1v + a2[sidx0 * H_ + h]);
            m = sv0;
        }
        for (int e2 = start + 64 + lane; e2 < end; e2 += 64)
            m = fmaxf(m, leaky(a1v + a2[csr_src[e2] * H_ + h]));
#pragma unroll
        for (int off = 32; off > 0; off >>= 1) m = fmaxf(m, __shfl_xor(m, off));
    }

    // pass 2: weights + broadcast + paired bf16 gather-accumulate
    float denom = 0.f, acc0 = 0.f, acc1 = 0.f;
    for (int base = start; base < end; base += 64) {
        int e = base + lane;
        float wgt = 0.f;
        int sidx = sidx0;
        if (base == start) {
            if (e < end) wgt = expf(sv0 - m);
        } else if (e < end) {
            sidx = csr_src[e];
            wgt = expf(leaky(a1v + a2[sidx * H_ + h]) - m);
        }
        denom += wgt;
        int cnt = min(64, end - base);
        if (FINAL) {
            // Dh=64: half-wave per edge, 2 edges per iteration
            int half = lane >> 5, idx = lane & 31;
            for (int i = 0; i < cnt; i += 2) {
                int j = i + half;
                float wj = (j < cnt) ? __shfl(wgt, j) : 0.f;
                int   sj = __shfl(sidx, (j < cnt) ? j : i);
                unsigned v = *(const unsigned*)(ft + (size_t)sj * ld + 2 * idx);
                acc0 += wj * bflo(v);
                acc1 += wj * bfhi(v);
            }
        } else {
            // Dh=128: full wave per edge, 2 edges in flight
            for (int i = 0; i < cnt; i += 2) {
                float w0 = __shfl(wgt, i);
                int   s0 = __shfl(sidx, i);
                float w1 = 0.f; int s1 = s0;
                if (i + 1 < cnt) { w1 = __shfl(wgt, i + 1); s1 = __shfl(sidx, i + 1); }
                unsigned v0 = *(const unsigned*)(ft + (size_t)s0 * ld + h * Dh + 2 * lane);
                unsigned v1 = *(const unsigned*)(ft + (size_t)s1 * ld + h * Dh + 2 * lane);
                acc0 += w0 * bflo(v0) + w1 * bflo(v1);
                acc1 += w0 * bfhi(v0) + w1 * bfhi(v1);
            }
        }
    }
#pragma unroll
    for (int off = 32; off > 0; off >>= 1) denom += __shfl_xor(denom, off);
    float inv = 1.f / denom;

    if (FINAL) {
        // combine the two half-wave partials (same element indices)
        acc0 += __shfl_xor(acc0, 32);
        acc1 += __shfl_xor(acc1, 32);
        float r0 = acc0 * inv, r1 = acc1 * inv;
        r0 = (r0 > 0.f) ? r0 : expm1f(r0);
        r1 = (r1 > 0.f) ? r1 : expm1f(r1);
        if (lane < 32)
            *(float2*)((float*)outp + obase + 2 * (lane & 31)) = make_float2(r0, r1);
    } else {
        float r0 = acc0 * inv, r1 = acc1 * inv;
        r0 = (r0 > 0.f) ? r0 : expm1f(r0);
        r1 = (r1 > 0.f) ? r1 : expm1f(r1);
        unsigned pk = (unsigned)f2bf(r0) | ((unsigned)f2bf(r1) << 16);
        *(unsigned*)((unsigned short*)outp + obase + 2 * lane) = pk;
    }
}

// ---------------- launch ----------------
extern "C" void kernel_launch(void* const* d_in, const int* in_sizes, int n_in,
                              void* d_out, int out_size, void* d_ws, size_t ws_size,
                              hipStream_t stream) {
    const float* features = (const float*)d_in[0];
    const int*   src      = (const int*)d_in[1];
    const int*   dst      = (const int*)d_in[2];
    const float* W0  = (const float*)d_in[3];
    const float* b0  = (const float*)d_in[4];
    const float* al0 = (const float*)d_in[5];
    const float* alb0= (const float*)d_in[6];
    const float* ar0 = (const float*)d_in[7];
    const float* arb0= (const float*)d_in[8];
    const float* W1  = (const float*)d_in[9];
    const float* b1  = (const float*)d_in[10];
    const float* al1 = (const float*)d_in[11];
    const float* alb1= (const float*)d_in[12];
    const float* ar1 = (const float*)d_in[13];
    const float* arb1= (const float*)d_in[14];
    const float* Wf  = (const float*)d_in[15];
    const float* bff = (const float*)d_in[16];
    const float* alf = (const float*)d_in[17];
    const float* albf= (const float*)d_in[18];
    const float* arf = (const float*)d_in[19];
    const float* arbf= (const float*)d_in[20];
    float* out = (float*)d_out;

    // workspace carve
    char* wp = (char*)d_ws;
    unsigned short* ft16  = (unsigned short*)wp;  wp += (size_t)N_NODES * 1024 * 2;
    unsigned short* xb16  = (unsigned short*)wp;  wp += (size_t)N_NODES * 1024 * 2;
    unsigned short* feat16= (unsigned short*)wp;  wp += (size_t)N_NODES * 512 * 2;
    unsigned short* w0t   = (unsigned short*)wp;  wp += (size_t)N_HEADS * D_HID * D_IN * 2;
    unsigned short* w1t   = (unsigned short*)wp;  wp += (size_t)N_HEADS * D_HID * 1024 * 2;
    unsigned short* wft   = (unsigned short*)wp;  wp += (size_t)N_CLS * 1024 * 2;
    float* a1             = (float*)wp;           wp += (size_t)N_NODES * N_HEADS * 4;
    float* a2             = (float*)wp;           wp += (size_t)N_NODES * N_HEADS * 4;
    int* counts = (int*)wp;                       wp += (size_t)N_NODES * 4;
    int* indptr = (int*)wp;                       wp += (size_t)(N_NODES + 1) * 4;
    int* cursor = (int*)wp;                       wp += (size_t)N_NODES * 4;
    int* csr    = (int*)wp;

    // ---- CSR build
    k_zero<<<(N_NODES + 255) / 256, 256, 0, stream>>>(counts, N_NODES);
    k_count<<<(N_EDGES + 255) / 256, 256, 0, stream>>>(dst, counts, N_EDGES);
    k_scan<<<1, 1024, 0, stream>>>(counts, indptr, cursor, N_NODES);
    k_scatter<<<(N_EDGES + 255) / 256, 256, 0, stream>>>(src, dst, cursor, csr, N_EDGES);

    // ---- conversions
    k_cvtA<<<(N_NODES * D_IN / 4 + 255) / 256, 256, 0, stream>>>(features, feat16, N_NODES * D_IN / 4);
    k_cvtW<<<dim3(D_IN / 64, D_HID / 64, N_HEADS), 256, 0, stream>>>(W0, w0t, D_IN, D_HID);
    k_cvtW<<<dim3(1024 / 64, D_HID / 64, N_HEADS), 256, 0, stream>>>(W1, w1t, 1024, D_HID);
    k_cvtW<<<dim3(1024 / 64, N_CLS / 64, 1), 256, 0, stream>>>(Wf, wft, 1024, N_CLS);

    const int gm = (N_NODES + 127) / 128;           // 157
    int nodeBlocks = (N_NODES + 3) / 4;             // 5000
    int aggBlocksH = (N_NODES * N_HEADS + 3) / 4;   // 40000

    // ---- layer 0
    k_gemm_bf16<128><<<dim3(gm, 1, N_HEADS), 256, 0, stream>>>(
        feat16, w0t, b0, ft16, N_NODES, D_IN, N_HEADS * D_HID);
    k_alogit<<<nodeBlocks, 256, 0, stream>>>(ft16, al0, alb0, ar0, arb0, a1, a2, N_HEADS, D_HID);
    k_aggregate<0><<<aggBlocksH, 256, 0, stream>>>(ft16, a1, a2, indptr, csr, xb16);

    // ---- layer 1
    k_gemm_bf16<128><<<dim3(gm, 1, N_HEADS), 256, 0, stream>>>(
        xb16, w1t, b1, ft16, N_NODES, 1024, N_HEADS * D_HID);
    k_alogit<<<nodeBlocks, 256, 0, stream>>>(ft16, al1, alb1, ar1, arb1, a1, a2, N_HEADS, D_HID);
    k_aggregate<0><<<aggBlocksH, 256, 0, stream>>>(ft16, a1, a2, indptr, csr, xb16);

    // ---- final layer (N=64, single head)
    k_gemm_bf16<64><<<dim3(gm, 1, 1), 256, 0, stream>>>(
        xb16, wft, bff, ft16, N_NODES, 1024, N_CLS);
    k_alogit<<<nodeBlocks, 256, 0, stream>>>(ft16, alf, albf, arf, arbf, a1, a2, 1, N_CLS);
    k_aggregate<1><<<nodeBlocks, 256, 0, stream>>>(ft16, a1, a2, indptr, csr, out);
}